// Round 1
// baseline (218.664 us; speedup 1.0000x reference)
//
#include <hip/hip_runtime.h>

// MaskLoss: per-image 2-means over pixel intensities + border-vote flip + MSE.
// B=128 images, 3x256x256 f32 each. One 1024-thread block per image; the
// 65536-pixel gray image lives in registers (64 floats/thread, unrolled).

constexpr int TPB  = 1024;
constexpr int NW   = TPB / 64;      // 16 waves per block
constexpr int NPIX = 65536;         // 256*256
constexpr int VPT  = NPIX / TPB;    // 64 values per thread
constexpr int V4   = VPT / 4;       // 16 float4 groups per thread
constexpr int KM_ITERS = 20;

__device__ __forceinline__ float waveSum(float v) {
#pragma unroll
    for (int off = 32; off > 0; off >>= 1) v += __shfl_down(v, off, 64);
    return v;
}
__device__ __forceinline__ float waveMin(float v) {
#pragma unroll
    for (int off = 32; off > 0; off >>= 1) v = fminf(v, __shfl_down(v, off, 64));
    return v;
}
__device__ __forceinline__ float waveMax(float v) {
#pragma unroll
    for (int off = 32; off > 0; off >>= 1) v = fmaxf(v, __shfl_down(v, off, 64));
    return v;
}

__global__ __launch_bounds__(TPB) void kmeans_mask_loss(
        const float* __restrict__ hr, const float* __restrict__ sr,
        float* __restrict__ ws) {
    const int img  = blockIdx.x;
    const int tid  = threadIdx.x;
    const int lane = tid & 63;
    const int wid  = tid >> 6;

    __shared__ float4 sm4[NW];
    __shared__ float  bc[4];

    const float* r = hr + (size_t)img * 3 * NPIX;
    const float* g = r + NPIX;
    const float* b = g + NPIX;

    // ---- load + grayscale (mean over 3 channels), register resident ----
    float v[VPT];
#pragma unroll
    for (int i = 0; i < V4; ++i) {
        const int p = 4 * tid + 4096 * i;
        float4 rr = *(const float4*)(r + p);
        float4 gg = *(const float4*)(g + p);
        float4 bb = *(const float4*)(b + p);
        v[4*i+0] = (rr.x + gg.x + bb.x) * (1.0f / 3.0f);
        v[4*i+1] = (rr.y + gg.y + bb.y) * (1.0f / 3.0f);
        v[4*i+2] = (rr.z + gg.z + bb.z) * (1.0f / 3.0f);
        v[4*i+3] = (rr.w + gg.w + bb.w) * (1.0f / 3.0f);
    }

    // ---- min / max / total-sum block reduction ----
    float mn = v[0], mx = v[0], sm = 0.0f;
#pragma unroll
    for (int i = 0; i < VPT; ++i) {
        mn = fminf(mn, v[i]); mx = fmaxf(mx, v[i]); sm += v[i];
    }
    mn = waveMin(mn); mx = waveMax(mx); sm = waveSum(sm);
    if (lane == 0) sm4[wid] = make_float4(mn, mx, sm, 0.0f);
    __syncthreads();
    if (wid == 0) {
        float4 x = (lane < NW) ? sm4[lane] : make_float4(3.0e38f, -3.0e38f, 0.0f, 0.0f);
        x.x = waveMin(x.x); x.y = waveMax(x.y); x.z = waveSum(x.z);
        if (lane == 0) { bc[0] = x.x; bc[1] = x.y; bc[2] = x.z; }
    }
    __syncthreads();
    float c0 = bc[0], c1 = bc[1];
    const float S = bc[2];

    // ---- Lloyd iterations; assignment==1 iff |x-c1| < |x-c0| (tie -> 0),
    //      i.e. x > midpoint when c1 >= c0. Early-exit on bitwise fixed point
    //      (subsequent iterations would be identical). ----
#pragma unroll 1
    for (int it = 0; it < KM_ITERS; ++it) {
        const float t = 0.5f * (c0 + c1);
        float s1 = 0.0f, n1 = 0.0f;
        if (c1 >= c0) {
#pragma unroll
            for (int i = 0; i < VPT; ++i)
                if (v[i] > t) { s1 += v[i]; n1 += 1.0f; }
        } else {
#pragma unroll
            for (int i = 0; i < VPT; ++i)
                if (v[i] < t) { s1 += v[i]; n1 += 1.0f; }
        }
        s1 = waveSum(s1); n1 = waveSum(n1);
        if (lane == 0) sm4[wid] = make_float4(s1, n1, 0.0f, 0.0f);
        __syncthreads();
        if (wid == 0) {
            float4 x = (lane < NW) ? sm4[lane] : make_float4(0.0f, 0.0f, 0.0f, 0.0f);
            x.x = waveSum(x.x); x.y = waveSum(x.y);
            if (lane == 0) {
                const float S1 = x.x, N1 = x.y;
                bc[1] = S1 / fmaxf(N1, 1.0f);
                bc[0] = (S - S1) / fmaxf((float)NPIX - N1, 1.0f);
            }
        }
        __syncthreads();
        const float nc0 = bc[0], nc1 = bc[1];
        const bool conv = (nc0 == c0) && (nc1 == c1);
        c0 = nc0; c1 = nc1;
        if (conv) break;
    }

    // ---- final assignment + border vote ----
    const float t  = 0.5f * (c0 + c1);
    const bool  hi = (c1 >= c0);
    float fc = 0.0f, lc = 0.0f, fr = 0.0f, lr = 0.0f;
#pragma unroll
    for (int i = 0; i < V4; ++i) {
#pragma unroll
        for (int j = 0; j < 4; ++j) {
            const int p   = 4 * tid + 4096 * i + j;
            const int col = p & 255;
            const int row = p >> 8;
            const bool code = hi ? (v[4*i+j] > t) : (v[4*i+j] < t);
            const float cf = code ? 1.0f : 0.0f;
            if (col == 0)   fc += cf;
            if (col == 255) lc += cf;
            if (row == 0)   fr += cf;
            if (row == 255) lr += cf;
        }
    }
    fc = waveSum(fc); lc = waveSum(lc); fr = waveSum(fr); lr = waveSum(lr);
    if (lane == 0) sm4[wid] = make_float4(fc, lc, fr, lr);
    __syncthreads();
    if (wid == 0) {
        float4 x = (lane < NW) ? sm4[lane] : make_float4(0.0f, 0.0f, 0.0f, 0.0f);
        x.x = waveSum(x.x); x.y = waveSum(x.y); x.z = waveSum(x.z); x.w = waveSum(x.w);
        if (lane == 0) {
            // num = (fr>W/2)+(lr>W/2)+(fc>H/2)+(lc>H/2); flip if num>=3
            const int num = (x.z > 128.0f) + (x.w > 128.0f) +
                            (x.x > 128.0f) + (x.y > 128.0f);
            bc[0] = (num >= 3) ? 1.0f : 0.0f;
        }
    }
    __syncthreads();
    const bool flip = (bc[0] != 0.0f);

    // ---- MSE vs sr_mask; mask = code XOR flip ----
    const float* srp = sr + (size_t)img * NPIX;
    float acc = 0.0f;
#pragma unroll
    for (int i = 0; i < V4; ++i) {
        const int p = 4 * tid + 4096 * i;
        float4 s = *(const float4*)(srp + p);
#pragma unroll
        for (int j = 0; j < 4; ++j) {
            const bool code = hi ? (v[4*i+j] > t) : (v[4*i+j] < t);
            const float m = (code != flip) ? 1.0f : 0.0f;
            const float sv = (j == 0) ? s.x : (j == 1) ? s.y : (j == 2) ? s.z : s.w;
            const float d = sv - m;
            acc += d * d;
        }
    }
    acc = waveSum(acc);
    if (lane == 0) sm4[wid] = make_float4(acc, 0.0f, 0.0f, 0.0f);
    __syncthreads();
    if (wid == 0) {
        float x = (lane < NW) ? sm4[lane].x : 0.0f;
        x = waveSum(x);
        if (lane == 0) ws[img] = x;
    }
}

__global__ void finalize_kernel(const float* __restrict__ ws, float* __restrict__ out) {
    const int lane = threadIdx.x;               // 64 threads, one wave
    float v = ws[lane] + ws[lane + 64];         // 128 per-image sums
    v = waveSum(v);
    if (lane == 0) out[0] = v * (1.0f / 8388608.0f);   // mean over 128*1*256*256
}

extern "C" void kernel_launch(void* const* d_in, const int* in_sizes, int n_in,
                              void* d_out, int out_size, void* d_ws, size_t ws_size,
                              hipStream_t stream) {
    const float* hr = (const float*)d_in[0];   // [128,3,256,256] f32
    const float* sr = (const float*)d_in[1];   // [128,1,256,256] f32
    float* out = (float*)d_out;                // scalar f32
    float* ws  = (float*)d_ws;                 // 128 per-image loss sums

    kmeans_mask_loss<<<128, TPB, 0, stream>>>(hr, sr, ws);
    finalize_kernel<<<1, 64, 0, stream>>>(ws, out);
}

// Round 2
// 209.300 us; speedup vs baseline: 1.0447x; 1.0447x over previous
//
#include <hip/hip_runtime.h>

// MaskLoss via per-image intensity histogram:
//   memset ws -> [A] gray+histogram (full chip) -> [B] suffix-scan + 20 Lloyd
//   iterations on 2048 bins (O(1)/iter) -> [C] border vote -> [D] MSE (full
//   chip) -> [E] finalize. ws usage ~2.11 MB.

constexpr int NB   = 2048;       // histogram bins over [0,1)
constexpr int NPIX = 65536;      // 256*256
constexpr int KM_ITERS = 20;

// ws byte offsets
constexpr size_t OFF_MINENC = 0;                      // 128 u32 (0xFFFFFFFF - bits(min))
constexpr size_t OFF_MAXBIT = 512;                    // 128 u32 (bits(max))
constexpr size_t OFF_TINFO  = 1024;                   // 128 float4 {t, hi, flip, pad}
constexpr size_t OFF_HCNT   = 4096;                   // 128*2048 u32 (1 MB)
constexpr size_t OFF_HSUM   = OFF_HCNT + (size_t)128 * NB * 4;   // 128*2048 f32 (1 MB)
constexpr size_t OFF_BSUM   = OFF_HSUM + (size_t)128 * NB * 4;   // 1024 f32
constexpr size_t MEMSET_BYTES = OFF_BSUM;             // blocksum fully overwritten

__device__ __forceinline__ float waveSum(float v) {
#pragma unroll
    for (int off = 32; off > 0; off >>= 1) v += __shfl_down(v, off, 64);
    return v;
}
__device__ __forceinline__ float waveMin(float v) {
#pragma unroll
    for (int off = 32; off > 0; off >>= 1) v = fminf(v, __shfl_down(v, off, 64));
    return v;
}
__device__ __forceinline__ float waveMax(float v) {
#pragma unroll
    for (int off = 32; off > 0; off >>= 1) v = fmaxf(v, __shfl_down(v, off, 64));
    return v;
}

// ---------------- [A] grayscale + histogram + min/max ----------------
// 1024 blocks x 256 threads; 8 blocks per image, 8192 px per block.
__global__ __launch_bounds__(256) void kA_hist(
        const float* __restrict__ hr, unsigned* __restrict__ minenc,
        unsigned* __restrict__ maxbits, unsigned* __restrict__ hcnt,
        float* __restrict__ hsum) {
    const int img = blockIdx.x >> 3, part = blockIdx.x & 7, tid = threadIdx.x;
    const int lane = tid & 63, wid = tid >> 6;

    __shared__ unsigned hcL[NB];
    __shared__ float    hsL[NB];
    __shared__ float    smn[4], smx[4];
    for (int j = tid; j < NB; j += 256) { hcL[j] = 0u; hsL[j] = 0.0f; }
    __syncthreads();

    const float* r = hr + (size_t)img * 3 * NPIX;
    const float* g = r + NPIX;
    const float* b = g + NPIX;

    float mn = 1e30f, mx = -1e30f;
#pragma unroll
    for (int i = 0; i < 8; ++i) {
        const int p = part * 8192 + i * 1024 + tid * 4;
        float4 rr = *(const float4*)(r + p);
        float4 gg = *(const float4*)(g + p);
        float4 bb = *(const float4*)(b + p);
        float x[4] = { (rr.x + gg.x + bb.x) * (1.0f / 3.0f),
                       (rr.y + gg.y + bb.y) * (1.0f / 3.0f),
                       (rr.z + gg.z + bb.z) * (1.0f / 3.0f),
                       (rr.w + gg.w + bb.w) * (1.0f / 3.0f) };
#pragma unroll
        for (int j = 0; j < 4; ++j) {
            mn = fminf(mn, x[j]); mx = fmaxf(mx, x[j]);
            int k = (int)(x[j] * (float)NB);
            k = max(0, min(NB - 1, k));
            atomicAdd(&hcL[k], 1u);
            atomicAdd(&hsL[k], x[j]);      // LDS float add (ds_add_f32 on CDNA)
        }
    }
    __syncthreads();

    // merge LDS hist into per-image global hist
    for (int j = tid; j < NB; j += 256) {
        unsigned c = hcL[j];
        if (c) {
            atomicAdd(&hcnt[(size_t)img * NB + j], c);
            unsafeAtomicAdd(&hsum[(size_t)img * NB + j], hsL[j]);
        }
    }

    // block min/max -> global atomics (positive floats: bit order == value order)
    mn = waveMin(mn); mx = waveMax(mx);
    if (lane == 0) { smn[wid] = mn; smx[wid] = mx; }
    __syncthreads();
    if (tid == 0) {
        float bmn = fminf(fminf(smn[0], smn[1]), fminf(smn[2], smn[3]));
        float bmx = fmaxf(fmaxf(smx[0], smx[1]), fmaxf(smx[2], smx[3]));
        atomicMax(&maxbits[img], __float_as_uint(bmx));
        atomicMax(&minenc[img], 0xFFFFFFFFu - __float_as_uint(bmn));
    }
}

// ---------------- [B] suffix scan + Lloyd on histogram ----------------
// 128 blocks x 256 threads; each thread owns 8 consecutive bins.
__global__ __launch_bounds__(256) void kB_lloyd(
        const unsigned* __restrict__ minenc, const unsigned* __restrict__ maxbits,
        const unsigned* __restrict__ hcnt, const float* __restrict__ hsum,
        float4* __restrict__ tinfo) {
    const int img = blockIdx.x, tid = threadIdx.x;
    __shared__ float sN[NB + 1], sS[NB + 1];
    __shared__ float tN[256], tS[256];

    const int base = tid * 8;
    float n8[8], s8[8];
#pragma unroll
    for (int u = 0; u < 8; ++u) {
        n8[u] = (float)hcnt[(size_t)img * NB + base + u];
        s8[u] = hsum[(size_t)img * NB + base + u];
    }
    float accN = 0.0f, accS = 0.0f;
#pragma unroll
    for (int u = 7; u >= 0; --u) {
        accN += n8[u]; n8[u] = accN;
        accS += s8[u]; s8[u] = accS;
    }
    tN[tid] = accN; tS[tid] = accS;
    __syncthreads();
    for (int off = 1; off < 256; off <<= 1) {
        float aN = 0.0f, aS = 0.0f;
        if (tid + off < 256) { aN = tN[tid + off]; aS = tS[tid + off]; }
        __syncthreads();
        tN[tid] += aN; tS[tid] += aS;
        __syncthreads();
    }
    const float exN = (tid < 255) ? tN[tid + 1] : 0.0f;
    const float exS = (tid < 255) ? tS[tid + 1] : 0.0f;
#pragma unroll
    for (int u = 0; u < 8; ++u) { sN[base + u] = n8[u] + exN; sS[base + u] = s8[u] + exS; }
    if (tid == 0) { sN[NB] = 0.0f; sS[NB] = 0.0f; }
    __syncthreads();

    if (tid == 0) {
        const float mn = __uint_as_float(0xFFFFFFFFu - minenc[img]);
        const float mx = __uint_as_float(maxbits[img]);
        const float Stot = sS[0];
        const float Ntot = (float)NPIX;
        float c0 = mn, c1 = mx;
#pragma unroll 1
        for (int it = 0; it < KM_ITERS; ++it) {
            const float t = 0.5f * (c0 + c1);
            float n1, s1;
            if (c1 == c0) { n1 = 0.0f; s1 = 0.0f; }
            else {
                const float f = t * (float)NB;
                int k = (int)floorf(f);
                k = max(0, min(NB - 1, k));
                float frac = (float)(k + 1) - f;          // fraction of bin k above t
                frac = fminf(fmaxf(frac, 0.0f), 1.0f);
                const float cntk = sN[k] - sN[k + 1];
                const float sumk = sS[k] - sS[k + 1];
                const float aN = sN[k + 1] + cntk * frac; // count of x > t (interp)
                const float aS = sS[k + 1] + sumk * frac; // sum   of x > t (interp)
                if (c1 > c0) { n1 = aN; s1 = aS; }
                else         { n1 = Ntot - aN; s1 = Stot - aS; }
            }
            const float c1n = s1 / fmaxf(n1, 1.0f);
            const float c0n = (Stot - s1) / fmaxf(Ntot - n1, 1.0f);
            if (c1n == c1 && c0n == c0) break;   // exact fixed point: rest are no-ops
            c0 = c0n; c1 = c1n;
        }
        float tf, hii;
        if (c1 == c0) { tf = -1e30f; hii = 0.0f; }   // lo-mode, never true -> all code 0
        else { tf = 0.5f * (c0 + c1); hii = (c1 > c0) ? 1.0f : 0.0f; }
        tinfo[img] = make_float4(tf, hii, 0.0f, 0.0f);
    }
}

// ---------------- [C] border vote ----------------
// 128 blocks x 256 threads; each thread handles one entry of each border.
__global__ __launch_bounds__(256) void kC_border(
        const float* __restrict__ hr, float4* __restrict__ tinfo) {
    const int img = blockIdx.x, tid = threadIdx.x;
    const int lane = tid & 63, wid = tid >> 6;
    __shared__ float4 sm[4];

    const float4 ti = tinfo[img];
    const float t = ti.x;
    const bool hi = (ti.y != 0.0f);

    const float* r = hr + (size_t)img * 3 * NPIX;
    const float* g = r + NPIX;
    const float* b = g + NPIX;

    auto codeAt = [&](int p) -> float {
        const float x = (r[p] + g[p] + b[p]) * (1.0f / 3.0f);
        const bool one = hi ? (x > t) : (x < t);
        return one ? 1.0f : 0.0f;
    };
    float fr = codeAt(tid);                 // row 0, col tid
    float lr = codeAt(255 * 256 + tid);     // row 255
    float fc = codeAt(tid * 256);           // col 0, row tid
    float lc = codeAt(tid * 256 + 255);     // col 255

    fr = waveSum(fr); lr = waveSum(lr); fc = waveSum(fc); lc = waveSum(lc);
    if (lane == 0) sm[wid] = make_float4(fr, lr, fc, lc);
    __syncthreads();
    if (tid == 0) {
        float FR = sm[0].x + sm[1].x + sm[2].x + sm[3].x;
        float LR = sm[0].y + sm[1].y + sm[2].y + sm[3].y;
        float FC = sm[0].z + sm[1].z + sm[2].z + sm[3].z;
        float LC = sm[0].w + sm[1].w + sm[2].w + sm[3].w;
        const int num = (FR > 128.0f) + (LR > 128.0f) + (FC > 128.0f) + (LC > 128.0f);
        tinfo[img].z = (num >= 3) ? 1.0f : 0.0f;
    }
}

// ---------------- [D] MSE ----------------
// 1024 blocks x 256 threads; 8 blocks per image.
__global__ __launch_bounds__(256) void kD_mse(
        const float* __restrict__ hr, const float* __restrict__ sr,
        const float4* __restrict__ tinfo, float* __restrict__ bsum) {
    const int img = blockIdx.x >> 3, part = blockIdx.x & 7, tid = threadIdx.x;
    const int lane = tid & 63, wid = tid >> 6;
    __shared__ float sm[4];

    const float4 ti = tinfo[img];
    const float t = ti.x;
    const bool hi   = (ti.y != 0.0f);
    const bool flip = (ti.z != 0.0f);

    const float* r = hr + (size_t)img * 3 * NPIX;
    const float* g = r + NPIX;
    const float* b = g + NPIX;
    const float* s = sr + (size_t)img * NPIX;

    float acc = 0.0f;
#pragma unroll
    for (int i = 0; i < 8; ++i) {
        const int p = part * 8192 + i * 1024 + tid * 4;
        float4 rr = *(const float4*)(r + p);
        float4 gg = *(const float4*)(g + p);
        float4 bb = *(const float4*)(b + p);
        float4 ss = *(const float4*)(s + p);
        float x[4] = { (rr.x + gg.x + bb.x) * (1.0f / 3.0f),
                       (rr.y + gg.y + bb.y) * (1.0f / 3.0f),
                       (rr.z + gg.z + bb.z) * (1.0f / 3.0f),
                       (rr.w + gg.w + bb.w) * (1.0f / 3.0f) };
        float sv[4] = { ss.x, ss.y, ss.z, ss.w };
#pragma unroll
        for (int j = 0; j < 4; ++j) {
            const bool one = hi ? (x[j] > t) : (x[j] < t);
            const float m = (one != flip) ? 1.0f : 0.0f;
            const float d = sv[j] - m;
            acc += d * d;
        }
    }
    acc = waveSum(acc);
    if (lane == 0) sm[wid] = acc;
    __syncthreads();
    if (tid == 0) bsum[blockIdx.x] = sm[0] + sm[1] + sm[2] + sm[3];
}

// ---------------- [E] finalize ----------------
__global__ __launch_bounds__(256) void kE_final(
        const float* __restrict__ bsum, float* __restrict__ out) {
    const int tid = threadIdx.x, lane = tid & 63, wid = tid >> 6;
    __shared__ float sm[4];
    float v = bsum[tid] + bsum[tid + 256] + bsum[tid + 512] + bsum[tid + 768];
    v = waveSum(v);
    if (lane == 0) sm[wid] = v;
    __syncthreads();
    if (tid == 0) out[0] = (sm[0] + sm[1] + sm[2] + sm[3]) * (1.0f / 8388608.0f);
}

extern "C" void kernel_launch(void* const* d_in, const int* in_sizes, int n_in,
                              void* d_out, int out_size, void* d_ws, size_t ws_size,
                              hipStream_t stream) {
    const float* hr = (const float*)d_in[0];   // [128,3,256,256] f32
    const float* sr = (const float*)d_in[1];   // [128,1,256,256] f32
    float* out = (float*)d_out;

    char* ws = (char*)d_ws;
    unsigned* minenc  = (unsigned*)(ws + OFF_MINENC);
    unsigned* maxbits = (unsigned*)(ws + OFF_MAXBIT);
    float4*   tinfo   = (float4*)(ws + OFF_TINFO);
    unsigned* hcnt    = (unsigned*)(ws + OFF_HCNT);
    float*    hsum    = (float*)(ws + OFF_HSUM);
    float*    bsum    = (float*)(ws + OFF_BSUM);

    hipMemsetAsync(d_ws, 0, MEMSET_BYTES, stream);
    kA_hist  <<<1024, 256, 0, stream>>>(hr, minenc, maxbits, hcnt, hsum);
    kB_lloyd <<< 128, 256, 0, stream>>>(minenc, maxbits, hcnt, hsum, tinfo);
    kC_border<<< 128, 256, 0, stream>>>(hr, tinfo);
    kD_mse   <<<1024, 256, 0, stream>>>(hr, sr, tinfo, bsum);
    kE_final <<<   1, 256, 0, stream>>>(bsum, out);
}

// Round 3
// 189.265 us; speedup vs baseline: 1.1553x; 1.1059x over previous
//
#include <hip/hip_runtime.h>

// MaskLoss via per-image counts-only intensity histogram + u16 gray cache:
//   memset(1MB) -> [A] gray->u16 + 2048-bin count hist + min/max
//               -> [B] suffix-scan + 20 Lloyd iters (O(1)/iter, interp)
//               -> [C] dual MSE (flip=0 and flip=1) + border counts
//               -> [D] finalize: border vote selects acc, reduce, mean.

constexpr int NB   = 2048;       // histogram bins (u16 >> 5)
constexpr int NPIX = 65536;      // 256*256
constexpr int KM_ITERS = 20;
constexpr float QINV  = 1.0f / 65536.0f;   // u16 -> gray
constexpr float BINW  = 1.0f / 2048.0f;    // bin width in gray units

// ws byte offsets
constexpr size_t OFF_MINENC = 0;                         // 128 u32: max(65535-u)
constexpr size_t OFF_MAXU   = 512;                       // 128 u32: max(u)
constexpr size_t OFF_TINFO  = 1024;                      // 128 float4 {t, hi, 0, 0}
constexpr size_t OFF_BORD   = 3072;                      // 128*4 u32 border counts
constexpr size_t OFF_HCNT   = 8192;                      // 128*2048 u32 (1 MB)
constexpr size_t OFF_GRAY   = OFF_HCNT + (size_t)128 * NB * 4;      // 128*65536 u16
constexpr size_t OFF_BSUM   = OFF_GRAY + (size_t)128 * NPIX * 2;    // 1024 float2
constexpr size_t MEMSET_BYTES = OFF_GRAY;                // zero minenc..hcnt

__device__ __forceinline__ float waveSumF(float v) {
#pragma unroll
    for (int off = 32; off > 0; off >>= 1) v += __shfl_down(v, off, 64);
    return v;
}
__device__ __forceinline__ unsigned waveMinU(unsigned v) {
#pragma unroll
    for (int off = 32; off > 0; off >>= 1) v = min(v, (unsigned)__shfl_down((int)v, off, 64));
    return v;
}
__device__ __forceinline__ unsigned waveMaxU(unsigned v) {
#pragma unroll
    for (int off = 32; off > 0; off >>= 1) v = max(v, (unsigned)__shfl_down((int)v, off, 64));
    return v;
}

// ---------------- [A] grayscale -> u16 + count histogram + min/max ----------
// 1024 blocks x 256 threads; 8 blocks/image, 8192 px/block (32 px/thread).
__global__ __launch_bounds__(256) void kA_hist(
        const float* __restrict__ hr, unsigned* __restrict__ minenc,
        unsigned* __restrict__ maxu, unsigned* __restrict__ hcnt,
        ushort* __restrict__ gray) {
    const int img = blockIdx.x >> 3, part = blockIdx.x & 7, tid = threadIdx.x;
    const int lane = tid & 63, wid = tid >> 6;

    __shared__ unsigned hcL[NB];
    __shared__ unsigned smn[4], smx[4];
    for (int j = tid; j < NB; j += 256) hcL[j] = 0u;
    __syncthreads();

    const float* r = hr + (size_t)img * 3 * NPIX;
    const float* g = r + NPIX;
    const float* b = g + NPIX;
    ushort* gp = gray + (size_t)img * NPIX;

    unsigned umn = 65535u, umx = 0u;
#pragma unroll
    for (int i = 0; i < 8; ++i) {
        const int p = part * 8192 + i * 1024 + tid * 4;
        float4 rr = *(const float4*)(r + p);
        float4 gg = *(const float4*)(g + p);
        float4 bb = *(const float4*)(b + p);
        float x[4] = { (rr.x + gg.x + bb.x) * (1.0f / 3.0f),
                       (rr.y + gg.y + bb.y) * (1.0f / 3.0f),
                       (rr.z + gg.z + bb.z) * (1.0f / 3.0f),
                       (rr.w + gg.w + bb.w) * (1.0f / 3.0f) };
        unsigned u[4];
#pragma unroll
        for (int j = 0; j < 4; ++j) {
            unsigned uu = (unsigned)(x[j] * 65536.0f);
            uu = min(uu, 65535u);
            u[j] = uu;
            umn = min(umn, uu); umx = max(umx, uu);
            atomicAdd(&hcL[uu >> 5], 1u);
        }
        ushort4 u4;
        u4.x = (ushort)u[0]; u4.y = (ushort)u[1];
        u4.z = (ushort)u[2]; u4.w = (ushort)u[3];
        *(ushort4*)(gp + p) = u4;
    }
    __syncthreads();

    for (int j = tid; j < NB; j += 256) {
        const unsigned c = hcL[j];
        if (c) atomicAdd(&hcnt[(size_t)img * NB + j], c);
    }

    umn = waveMinU(umn); umx = waveMaxU(umx);
    if (lane == 0) { smn[wid] = umn; smx[wid] = umx; }
    __syncthreads();
    if (tid == 0) {
        const unsigned bmn = min(min(smn[0], smn[1]), min(smn[2], smn[3]));
        const unsigned bmx = max(max(smx[0], smx[1]), max(smx[2], smx[3]));
        atomicMax(&maxu[img], bmx);
        atomicMax(&minenc[img], 65535u - bmn);
    }
}

// ---------------- [B] suffix scan + Lloyd on histogram ----------------
// 128 blocks x 256 threads; each thread owns 8 consecutive bins.
__global__ __launch_bounds__(256) void kB_lloyd(
        const unsigned* __restrict__ minenc, const unsigned* __restrict__ maxu,
        const unsigned* __restrict__ hcnt, float4* __restrict__ tinfo) {
    const int img = blockIdx.x, tid = threadIdx.x;
    __shared__ float sN[NB + 1], sS[NB + 1];
    __shared__ float tN[256], tS[256];

    const int base = tid * 8;
    float n8[8], s8[8];
#pragma unroll
    for (int u = 0; u < 8; ++u) {
        const float c = (float)hcnt[(size_t)img * NB + base + u];
        n8[u] = c;
        s8[u] = c * (((float)(base + u) + 0.484375f) * BINW);  // mean u in bin = 32k+15.5
    }
    float accN = 0.0f, accS = 0.0f;
#pragma unroll
    for (int u = 7; u >= 0; --u) {
        accN += n8[u]; n8[u] = accN;
        accS += s8[u]; s8[u] = accS;
    }
    tN[tid] = accN; tS[tid] = accS;
    __syncthreads();
    for (int off = 1; off < 256; off <<= 1) {
        float aN = 0.0f, aS = 0.0f;
        if (tid + off < 256) { aN = tN[tid + off]; aS = tS[tid + off]; }
        __syncthreads();
        tN[tid] += aN; tS[tid] += aS;
        __syncthreads();
    }
    const float exN = (tid < 255) ? tN[tid + 1] : 0.0f;
    const float exS = (tid < 255) ? tS[tid + 1] : 0.0f;
#pragma unroll
    for (int u = 0; u < 8; ++u) { sN[base + u] = n8[u] + exN; sS[base + u] = s8[u] + exS; }
    if (tid == 0) { sN[NB] = 0.0f; sS[NB] = 0.0f; }
    __syncthreads();

    if (tid == 0) {
        float c0 = (float)(65535u - minenc[img]) * QINV;
        float c1 = (float)maxu[img] * QINV;
        const float Stot = sS[0];
        const float Ntot = (float)NPIX;
#pragma unroll 1
        for (int it = 0; it < KM_ITERS; ++it) {
            const float t = 0.5f * (c0 + c1);
            float n1, s1;
            if (c1 == c0) { n1 = 0.0f; s1 = 0.0f; }
            else {
                const float f = t * (float)NB;
                int k = (int)floorf(f);
                k = max(0, min(NB - 1, k));
                float frac = (float)(k + 1) - f;             // fraction of bin k above t
                frac = fminf(fmaxf(frac, 0.0f), 1.0f);
                const float cntk = sN[k] - sN[k + 1];
                const float aN = sN[k + 1] + cntk * frac;    // count of x > t
                // in-bin sum above t: cnt*frac * midpoint(t, binEnd), uniform model
                const float aS = sS[k + 1] +
                                 cntk * frac * 0.5f * (t + (float)(k + 1) * BINW);
                if (c1 > c0) { n1 = aN; s1 = aS; }
                else         { n1 = Ntot - aN; s1 = Stot - aS; }
            }
            const float c1n = s1 / fmaxf(n1, 1.0f);
            const float c0n = (Stot - s1) / fmaxf(Ntot - n1, 1.0f);
            if (c1n == c1 && c0n == c0) break;   // exact fixed point
            c0 = c0n; c1 = c1n;
        }
        float tf, hii;
        if (c1 == c0) { tf = -1e30f; hii = 0.0f; }   // lo-mode, never true -> all code 0
        else { tf = 0.5f * (c0 + c1); hii = (c1 > c0) ? 1.0f : 0.0f; }
        tinfo[img] = make_float4(tf, hii, 0.0f, 0.0f);
    }
}

// ---------------- [C] dual MSE + border counts ----------------
// 1024 blocks x 256 threads; 8 blocks/image, 32 px/thread.
__global__ __launch_bounds__(256) void kC_mse(
        const ushort* __restrict__ gray, const float* __restrict__ sr,
        const float4* __restrict__ tinfo, unsigned* __restrict__ bord,
        float2* __restrict__ bsum) {
    const int img = blockIdx.x >> 3, part = blockIdx.x & 7, tid = threadIdx.x;
    const int lane = tid & 63, wid = tid >> 6;
    __shared__ float sA0[4], sA1[4];
    __shared__ float4 sB[4];

    const float4 ti = tinfo[img];
    const float t = ti.x;
    const bool hi = (ti.y != 0.0f);

    const ushort* gp = gray + (size_t)img * NPIX;
    const float*  sp = sr   + (size_t)img * NPIX;

    float a0 = 0.0f, a1 = 0.0f;
    float fr = 0.0f, lr = 0.0f, fc = 0.0f, lc = 0.0f;
#pragma unroll
    for (int i = 0; i < 8; ++i) {
        const int p = part * 8192 + i * 1024 + tid * 4;
        ushort4 u4 = *(const ushort4*)(gp + p);
        float4  ss = *(const float4*)(sp + p);
        const unsigned uu[4] = { u4.x, u4.y, u4.z, u4.w };
        const float    sv[4] = { ss.x, ss.y, ss.z, ss.w };
        const int row = p >> 8;             // same row for all 4 (p%256 <= 252)
#pragma unroll
        for (int j = 0; j < 4; ++j) {
            const float x = (float)uu[j] * QINV;
            const bool one = hi ? (x > t) : (x < t);
            const float m = one ? 1.0f : 0.0f;
            const float d0 = sv[j] - m;
            const float d1 = sv[j] - (1.0f - m);
            a0 += d0 * d0;
            a1 += d1 * d1;
            const int col = (p & 255) + j;
            if (col == 0)   fc += m;
            if (col == 255) lc += m;
            if (row == 0)   fr += m;
            if (row == 255) lr += m;
        }
    }
    a0 = waveSumF(a0); a1 = waveSumF(a1);
    fr = waveSumF(fr); lr = waveSumF(lr); fc = waveSumF(fc); lc = waveSumF(lc);
    if (lane == 0) { sA0[wid] = a0; sA1[wid] = a1; sB[wid] = make_float4(fr, lr, fc, lc); }
    __syncthreads();
    if (tid == 0) {
        bsum[blockIdx.x] = make_float2(sA0[0] + sA0[1] + sA0[2] + sA0[3],
                                       sA1[0] + sA1[1] + sA1[2] + sA1[3]);
        const float FR = sB[0].x + sB[1].x + sB[2].x + sB[3].x;
        const float LR = sB[0].y + sB[1].y + sB[2].y + sB[3].y;
        const float FC = sB[0].z + sB[1].z + sB[2].z + sB[3].z;
        const float LC = sB[0].w + sB[1].w + sB[2].w + sB[3].w;
        unsigned* bb = bord + (size_t)img * 4;
        if (FR > 0.5f) atomicAdd(&bb[0], (unsigned)(FR + 0.5f));
        if (LR > 0.5f) atomicAdd(&bb[1], (unsigned)(LR + 0.5f));
        if (FC > 0.5f) atomicAdd(&bb[2], (unsigned)(FC + 0.5f));
        if (LC > 0.5f) atomicAdd(&bb[3], (unsigned)(LC + 0.5f));
    }
}

// ---------------- [D] finalize: border vote + global reduce ----------------
__global__ __launch_bounds__(256) void kD_final(
        const unsigned* __restrict__ bord, const float2* __restrict__ bsum,
        float* __restrict__ out) {
    const int tid = threadIdx.x, lane = tid & 63, wid = tid >> 6;
    __shared__ float flipS[128];
    __shared__ float sm[4];
    if (tid < 128) {
        const unsigned* bb = bord + (size_t)tid * 4;
        const int num = (bb[0] > 128u) + (bb[1] > 128u) + (bb[2] > 128u) + (bb[3] > 128u);
        flipS[tid] = (num >= 3) ? 1.0f : 0.0f;
    }
    __syncthreads();
    float acc = 0.0f;
#pragma unroll
    for (int q = 0; q < 4; ++q) {
        const int e = tid * 4 + q;          // 1024 block sums, 8 per image
        const float2 v = bsum[e];
        acc += (flipS[e >> 3] != 0.0f) ? v.y : v.x;
    }
    acc = waveSumF(acc);
    if (lane == 0) sm[wid] = acc;
    __syncthreads();
    if (tid == 0) out[0] = (sm[0] + sm[1] + sm[2] + sm[3]) * (1.0f / 8388608.0f);
}

extern "C" void kernel_launch(void* const* d_in, const int* in_sizes, int n_in,
                              void* d_out, int out_size, void* d_ws, size_t ws_size,
                              hipStream_t stream) {
    const float* hr = (const float*)d_in[0];   // [128,3,256,256] f32
    const float* sr = (const float*)d_in[1];   // [128,1,256,256] f32
    float* out = (float*)d_out;

    char* ws = (char*)d_ws;
    unsigned* minenc = (unsigned*)(ws + OFF_MINENC);
    unsigned* maxu   = (unsigned*)(ws + OFF_MAXU);
    float4*   tinfo  = (float4*)(ws + OFF_TINFO);
    unsigned* bord   = (unsigned*)(ws + OFF_BORD);
    unsigned* hcnt   = (unsigned*)(ws + OFF_HCNT);
    ushort*   gray   = (ushort*)(ws + OFF_GRAY);
    float2*   bsum   = (float2*)(ws + OFF_BSUM);

    hipMemsetAsync(d_ws, 0, MEMSET_BYTES, stream);
    kA_hist <<<1024, 256, 0, stream>>>(hr, minenc, maxu, hcnt, gray);
    kB_lloyd<<< 128, 256, 0, stream>>>(minenc, maxu, hcnt, tinfo);
    kC_mse  <<<1024, 256, 0, stream>>>(gray, sr, tinfo, bord, bsum);
    kD_final<<<   1, 256, 0, stream>>>(bord, bsum, out);
}